// Round 20
// baseline (19.572 us; speedup 1.0000x reference)
//
#include <hip/hip_runtime.h>
#include <math.h>

// ---------------------------------------------------------------------------
// Z_exp = Tr(M rho^x4) = degree-4 poly in Bloch (x,y,z), 35 monomials.
// Model (R10-R19): chain = per-lane dynamic ops x effective LDS latency;
// latency set by waves/SIMD. All prior variants ran 1 block/CU (4 waves/
// SIMD). R20: R17's exact chain at 1 element/thread -> 512 blocks =
// 2 blocks/CU (launch_bounds(1024,8) caps VGPR<=64) -> 8 waves/SIMD,
// two interleaved redundant chains per CU hide each other's latency.
// ---------------------------------------------------------------------------

struct cpx { float re, im; };

__device__ __forceinline__ cpx cmul(cpx a, cpx b) {
    return { a.re * b.re - a.im * b.im, a.re * b.im + a.im * b.re };
}
__device__ __forceinline__ cpx cfma_(cpx acc, cpx a, cpx b) {
    acc.re += a.re * b.re - a.im * b.im;
    acc.im += a.re * b.im + a.im * b.re;
    return acc;
}

// block barrier, LDS-only drain (no vmcnt -> prefetch stays in flight)
#define BAR() do { asm volatile("s_waitcnt lgkmcnt(0)" ::: "memory"); \
                   __builtin_amdgcn_sched_barrier(0);                 \
                   __builtin_amdgcn_s_barrier(); } while (0)

// ---- compile-time Pauli-string -> monomial grouping (data-independent) ----
struct MonoTab { unsigned char cnt[125]; unsigned char idx[125][24]; };

constexpr int mono_of(int p) {
    int a = 0, b = 0, c = 0;
    for (int k = 0; k < 4; ++k) {
        const int pk = (p >> (2 * k)) & 3;   // 0=I,1=X,2=Y,3=Z
        a += (pk == 1); b += (pk == 2); c += (pk == 3);
    }
    return (a * 5 + b) * 5 + c;
}
constexpr MonoTab build_tab() {
    MonoTab t{};
    for (int m = 0; m < 125; ++m) {
        t.cnt[m] = 0;
        for (int k = 0; k < 24; ++k) t.idx[m][k] = 0;
    }
    for (int p = 0; p < 256; ++p) {          // ascending p: fixed sum order
        const int m = mono_of(p);
        t.idx[m][t.cnt[m]++] = (unsigned char)p;
    }
    return t;
}
__constant__ const MonoTab TAB = build_tab();

__global__ __launch_bounds__(1024, 8) void fused_kernel(
    const float2* __restrict__ in2, const float* __restrict__ w_U,
    const float* __restrict__ w_RXZX, const float* __restrict__ scale_p,
    const float* __restrict__ bias_p, float* __restrict__ out, int B)
{
    __shared__ cpx   R[24][2][2];
    __shared__ float ISc[6], ISs[6];
    __shared__ cpx   L[6][16][16];
    __shared__ cpx   Pp[4][3][16][16];   // phase-3 partials (reused as PART)
    __shared__ cpx   P1[3][16][16];
    __shared__ cpx   Dm[16][16];
    __shared__ cpx   Wf[16][16];
    __shared__ cpx   Mm[16][16];
    __shared__ float cpp[256][4];        // trace partials, q innermost
    __shared__ float cf[125];

    cpx (*PART)[16][16] = (cpx(*)[16][16])Pp;   // reuse Pp after phase 3b

    const int tid = threadIdx.x;
    const int idx = blockIdx.x * 1024 + tid;    // ONE element per thread
    const int q  = tid >> 8;                    // k-quarter 0..3
    const int ct = tid & 255;
    const int i = ct >> 4, j = ct & 15;
    const int k0 = q << 2;

    // prefetch only (no vmcnt drain until the eval tail uses it)
    float2 f = { 0.f, 0.f };
    if (idx < B) f = in2[idx];

    // ---- Phase 1: 2x2 RXZX gates + iSWAP params ----
    if (tid < 24) {
        const float ta = w_RXZX[tid * 3 + 0];
        const float tb = w_RXZX[tid * 3 + 1];
        const float tc = w_RXZX[tid * 3 + 2];
        float sa, ca, sb, cb, sc, cc;
        sincosf(0.5f * ta, &sa, &ca);
        sincosf(0.5f * tb, &sb, &cb);
        sincosf(0.5f * tc, &sc, &cc);
        // RX(t)=[[c,-is],[-is,c]], RZ(t)=diag(c-is,c+is); g = RX(a)RZ(b)RX(c)
        const cpx e0 = { cb, -sb };
        const cpx e1 = { cb,  sb };
        const cpx T00 = { e0.re * cc, e0.im * cc };
        const cpx T01 = { -e0.im * (-sc), e0.re * (-sc) };
        const cpx T10 = { -e1.im * (-sc), e1.re * (-sc) };
        const cpx T11 = { e1.re * cc, e1.im * cc };
        R[tid][0][0] = { ca * T00.re + sa * T10.im, ca * T00.im - sa * T10.re };
        R[tid][0][1] = { ca * T01.re + sa * T11.im, ca * T01.im - sa * T11.re };
        R[tid][1][0] = { sa * T00.im + ca * T10.re, -sa * T00.re + ca * T10.im };
        R[tid][1][1] = { sa * T01.im + ca * T11.re, -sa * T01.re + ca * T11.im };
    } else if (tid < 30) {
        const int l = tid - 24;
        float s, c;
        sincosf(w_U[l], &s, &c);
        ISc[l] = c;
        ISs[l] = s;
    }
    BAR();

    // ---- Phase 2: L[l] build; group q handles l = q, q+4 ----
    for (int l = q; l < 6; l += 4) {
        const int code = (int)((0xD89C8DC98DC9ULL >> (8 * l)) & 0xFF);
        const int qa = code & 3, qb = (code >> 2) & 3;
        const int qr = (code >> 4) & 3, qs = (code >> 6) & 3;
        const int uAi = (((i >> (3 - qa)) & 1) << 1) | ((i >> (3 - qb)) & 1);
        const int uAj = (((j >> (3 - qa)) & 1) << 1) | ((j >> (3 - qb)) & 1);
        const int uBi = (((i >> (3 - qr)) & 1) << 1) | ((i >> (3 - qs)) & 1);
        const int uBj = (((j >> (3 - qr)) & 1) << 1) | ((j >> (3 - qs)) & 1);
        const int ra = l * 4 + qa, rb = l * 4 + qb;
        cpx ga;
        if (uAj == 0)      ga = cmul(R[ra][uAi >> 1][0], R[rb][uAi & 1][0]);
        else if (uAj == 3) ga = cmul(R[ra][uAi >> 1][1], R[rb][uAi & 1][1]);
        else {
            const cpx k1 = cmul(R[ra][uAi >> 1][0], R[rb][uAi & 1][1]);
            const cpx k2 = cmul(R[ra][uAi >> 1][1], R[rb][uAi & 1][0]);
            const cpx tc = (uAj == 1) ? k1 : k2;   // * cos
            const cpx ts = (uAj == 1) ? k2 : k1;   // * i sin
            const float c = ISc[l], s = ISs[l];
            ga.re = c * tc.re - s * ts.im;
            ga.im = c * tc.im + s * ts.re;
        }
        const cpx gb = cmul(R[l * 4 + qr][uBi >> 1][uBj >> 1],
                            R[l * 4 + qs][uBi & 1][uBj & 1]);
        L[l][i][j] = cmul(ga, gb);
    }
    BAR();

    // ---- Phase 3: Pp[q][m] = quarter-k partial of L[2m+1]*L[2m] ----
    {
        cpx a0 = {0.f, 0.f}, a1 = {0.f, 0.f}, a2 = {0.f, 0.f};
        #pragma unroll
        for (int kk = 0; kk < 4; ++kk) {
            const int k = k0 + kk;
            a0 = cfma_(a0, L[1][i][k], L[0][k][j]);
            a1 = cfma_(a1, L[3][i][k], L[2][k][j]);
            a2 = cfma_(a2, L[5][i][k], L[4][k][j]);
        }
        Pp[q][0][i][j] = a0; Pp[q][1][i][j] = a1; Pp[q][2][i][j] = a2;
    }
    BAR();

    // ---- Phase 3b: reduce 4 partials (768 items, ascending q order) ----
    if (tid < 768) {
        const int m = tid >> 8, e = tid & 255, i2 = e >> 4, j2 = e & 15;
        cpx s = Pp[0][m][i2][j2];
        #pragma unroll
        for (int u = 1; u < 4; ++u) {
            const cpx t = Pp[u][m][i2][j2];
            s.re += t.re; s.im += t.im;
        }
        P1[m][i2][j2] = s;
    }
    BAR();

    // ---- Phase 4: PART[q] = quarter-k partial of P1[1]*P1[0] ----
    {
        cpx acc = {0.f, 0.f};
        #pragma unroll
        for (int kk = 0; kk < 4; ++kk) {
            const int k = k0 + kk;
            acc = cfma_(acc, P1[1][i][k], P1[0][k][j]);
        }
        PART[q][i][j] = acc;
    }
    BAR();
    if (tid < 256) {
        cpx s = PART[0][i][j];
        #pragma unroll
        for (int u = 1; u < 4; ++u) {
            const cpx t = PART[u][i][j];
            s.re += t.re; s.im += t.im;
        }
        Dm[i][j] = s;
    }
    BAR();

    // ---- Phase 5: W = P1[2]*D (same split) ----
    {
        cpx acc = {0.f, 0.f};
        #pragma unroll
        for (int kk = 0; kk < 4; ++kk) {
            const int k = k0 + kk;
            acc = cfma_(acc, P1[2][i][k], Dm[k][j]);
        }
        PART[q][i][j] = acc;
    }
    BAR();
    if (tid < 256) {
        cpx s = PART[0][i][j];
        #pragma unroll
        for (int u = 1; u < 4; ++u) {
            const cpx t = PART[u][i][j];
            s.re += t.re; s.im += t.im;
        }
        Wf[i][j] = s;
    }
    BAR();

    // ---- Phase 6: M[i][j] = sum_k zk conj(W[k][i]) W[k][j] (same split) ----
    {
        cpx acc = {0.f, 0.f};
        #pragma unroll
        for (int kk = 0; kk < 4; ++kk) {
            const int k = k0 + kk;
            const float zk = (k < 8) ? 1.f : -1.f;
            const cpx a = Wf[k][i];
            const cpx b = Wf[k][j];
            acc.re += zk * (a.re * b.re + a.im * b.im);   // conj(a)*b
            acc.im += zk * (a.re * b.im - a.im * b.re);
        }
        PART[q][i][j] = acc;
    }
    BAR();
    if (tid < 256) {
        cpx s = PART[0][i][j];
        #pragma unroll
        for (int u = 1; u < 4; ++u) {
            const cpx t = PART[u][i][j];
            s.re += t.re; s.im += t.im;
        }
        Mm[i][j] = s;
    }
    BAR();

    // ---- Phase 7: Pauli-trace partials over col quarter (p = ct) ----
    {
        const int p = ct;
        float accre = 0.f;
        #pragma unroll
        for (int cc = 0; cc < 4; ++cc) {
            const int col = k0 + cc;
            int row = 0;
            cpx val = {1.f, 0.f};
            #pragma unroll
            for (int k = 0; k < 4; ++k) {
                const int pk = (p >> (6 - 2 * k)) & 3;
                const int b = (col >> (3 - k)) & 1;
                int rb = b;
                if (pk == 1) {
                    rb = b ^ 1;
                } else if (pk == 2) {
                    rb = b ^ 1;
                    const cpx fc = {0.f, b ? -1.f : 1.f};
                    val = cmul(val, fc);
                } else if (pk == 3) {
                    if (b) { val.re = -val.re; val.im = -val.im; }
                }
                row |= rb << (3 - k);
            }
            const cpx mv = Mm[col][row];
            accre += mv.re * val.re - mv.im * val.im;
        }
        cpp[p][q] = accre;
    }
    BAR();

    // ---- Phase 8: collapse with inline 4-partial sums (R14 order) ----
    if (tid < 125) {
        const int cnt = TAB.cnt[tid];
        float s = 0.f;
        for (int k = 0; k < cnt; ++k) {        // ascending: deterministic
            const float* v = cpp[TAB.idx[tid][k]];
            s += (v[0] + v[1] + v[2] + v[3]) * (1.f / 16.f);
        }
        cf[tid] = s;
    }
    BAR();

    // ---- eval tail: 1 element per thread ----
    if (idx >= B) return;
    const float scale = scale_p[0], bias = bias_p[0];

    float s0, c0, s1, c1;
    sincosf(f.x, &s0, &c0);                    // vmcnt waited here, hidden
    sincosf(f.y, &s1, &c1);
    const float x = s1 * c0, y = s1 * s0, z = c1;

    float xp[5], yp[5], zp[5];
    xp[0] = yp[0] = zp[0] = 1.f;
    #pragma unroll
    for (int k = 1; k < 5; ++k) {
        xp[k] = xp[k - 1] * x;
        yp[k] = yp[k - 1] * y;
        zp[k] = zp[k - 1] * z;
    }

    float Z = 0.f;
    #pragma unroll
    for (int a = 0; a <= 4; ++a)
        #pragma unroll
        for (int b = 0; b <= 4 - a; ++b)
            #pragma unroll
            for (int c = 0; c <= 4 - a - b; ++c)
                Z = fmaf(cf[(a * 5 + b) * 5 + c], xp[a] * yp[b] * zp[c], Z);

    const float noise = 0.04472135954999579f * (Z * Z - 1.f) * 0.25f;
    out[idx] = scale * (Z + noise) + bias;
}

extern "C" void kernel_launch(void* const* d_in, const int* in_sizes, int n_in,
                              void* d_out, int out_size, void* d_ws, size_t ws_size,
                              hipStream_t stream) {
    const float* inputs  = (const float*)d_in[0];   // [B,2] f32
    const float* w_U     = (const float*)d_in[1];   // [6]
    const float* w_RXZX  = (const float*)d_in[2];   // [6,4,3]
    const float* scale_p = (const float*)d_in[3];   // [1]
    const float* bias_p  = (const float*)d_in[4];   // [1]
    float* out = (float*)d_out;

    const int B = in_sizes[0] / 2;                  // elements
    const int nblocks = (B + 1023) / 1024;          // 512 -> 2 blocks/CU

    fused_kernel<<<nblocks, 1024, 0, stream>>>(
        (const float2*)inputs, w_U, w_RXZX, scale_p, bias_p, out, B);
}

// Round 21
// 17.303 us; speedup vs baseline: 1.1311x; 1.1311x over previous
//
#include <hip/hip_runtime.h>
#include <math.h>

// ---------------------------------------------------------------------------
// Z_exp = Tr(M rho^x4) = degree-4 poly in Bloch (x,y,z), 35 monomials.
// Model (R10-R20): cost = launch + sum(phases: barrier floor + per-lane ops)
// + tail; optimum shape = 256 blocks x 1024 thr, 4-way k-split (R14/R17,
// 16.6us). Grid must be <= 256 (R20). Adding per-lane ops to cut phases
// always loses (R15/R16/R18/R19). R21: remove the ONE barrier that can go
// for free -- per-wave gate build (<=10 lanes build their own q-group's
// gates, same per-lane cost) makes gates->L wave-local: WSYNC, not BAR.
// 13 -> 12 barriers, everything else verbatim R17.
// ---------------------------------------------------------------------------

struct cpx { float re, im; };

__device__ __forceinline__ cpx cmul(cpx a, cpx b) {
    return { a.re * b.re - a.im * b.im, a.re * b.im + a.im * b.re };
}
__device__ __forceinline__ cpx cfma_(cpx acc, cpx a, cpx b) {
    acc.re += a.re * b.re - a.im * b.im;
    acc.im += a.re * b.im + a.im * b.re;
    return acc;
}

// block barrier, LDS-only drain (no vmcnt -> prefetch stays in flight)
#define BAR() do { asm volatile("s_waitcnt lgkmcnt(0)" ::: "memory"); \
                   __builtin_amdgcn_sched_barrier(0);                 \
                   __builtin_amdgcn_s_barrier(); } while (0)
// wave-local sync (R12-verified): own ds writes visible to own lanes
#define WSYNC() do { asm volatile("s_waitcnt lgkmcnt(0)" ::: "memory"); \
                     __builtin_amdgcn_sched_barrier(0); } while (0)

// ---- compile-time Pauli-string -> monomial grouping (data-independent) ----
struct MonoTab { unsigned char cnt[125]; unsigned char idx[125][24]; };

constexpr int mono_of(int p) {
    int a = 0, b = 0, c = 0;
    for (int k = 0; k < 4; ++k) {
        const int pk = (p >> (2 * k)) & 3;   // 0=I,1=X,2=Y,3=Z
        a += (pk == 1); b += (pk == 2); c += (pk == 3);
    }
    return (a * 5 + b) * 5 + c;
}
constexpr MonoTab build_tab() {
    MonoTab t{};
    for (int m = 0; m < 125; ++m) {
        t.cnt[m] = 0;
        for (int k = 0; k < 24; ++k) t.idx[m][k] = 0;
    }
    for (int p = 0; p < 256; ++p) {          // ascending p: fixed sum order
        const int m = mono_of(p);
        t.idx[m][t.cnt[m]++] = (unsigned char)p;
    }
    return t;
}
__constant__ const MonoTab TAB = build_tab();

__global__ __launch_bounds__(1024) void fused_kernel(
    const float4* __restrict__ in4, const float* __restrict__ w_U,
    const float* __restrict__ w_RXZX, const float* __restrict__ scale_p,
    const float* __restrict__ bias_p, float2* __restrict__ out2, int B2)
{
    __shared__ cpx   Rw[16][8][2][2];    // per-wave gate slots (layer half*4+qb)
    __shared__ float ISw[16][2][2];      // per-wave iSWAP {cos,sin} per half
    __shared__ cpx   L[6][16][16];
    __shared__ cpx   Pp[4][3][16][16];   // phase-3 partials (reused as PART)
    __shared__ cpx   P1[3][16][16];
    __shared__ cpx   Dm[16][16];
    __shared__ cpx   Wf[16][16];
    __shared__ cpx   Mm[16][16];
    __shared__ float cpp[256][4];        // trace partials, q innermost
    __shared__ float cf[125];

    cpx (*PART)[16][16] = (cpx(*)[16][16])Pp;   // reuse Pp after phase 3b

    const int tid = threadIdx.x;
    const int idx = blockIdx.x * 1024 + tid;    // float4 unit (2 elements)
    const int wv = tid >> 6;                    // wave 0..15
    const int lane = tid & 63;
    const int q  = tid >> 8;                    // k-quarter 0..3 (= wv>>2)
    const int ct = tid & 255;
    const int i = ct >> 4, j = ct & 15;
    const int k0 = q << 2;

    // prefetch only (no vmcnt drain until the eval tail uses it)
    float4 f = make_float4(0.f, 0.f, 0.f, 0.f);
    if (idx < B2) f = in4[idx];

    // ---- Phase 1 (wave-local, NO block barrier): each wave builds the
    //      gates for its q-group's layers l = q (slots 0-3), q+4 (slots 4-7)
    if (lane < 8) {
        const int l = q + (lane >> 2) * 4;      // layer for this slot
        if (l < 6) {
            const int g = l * 4 + (lane & 3);   // RXZX gate index
            const float ta = w_RXZX[g * 3 + 0];
            const float tb = w_RXZX[g * 3 + 1];
            const float tc = w_RXZX[g * 3 + 2];
            float sa, ca, sb, cb, sc, cc;
            sincosf(0.5f * ta, &sa, &ca);
            sincosf(0.5f * tb, &sb, &cb);
            sincosf(0.5f * tc, &sc, &cc);
            // RX(t)=[[c,-is],[-is,c]], RZ(t)=diag(c-is,c+is); g=RX(a)RZ(b)RX(c)
            const cpx e0 = { cb, -sb };
            const cpx e1 = { cb,  sb };
            const cpx T00 = { e0.re * cc, e0.im * cc };
            const cpx T01 = { -e0.im * (-sc), e0.re * (-sc) };
            const cpx T10 = { -e1.im * (-sc), e1.re * (-sc) };
            const cpx T11 = { e1.re * cc, e1.im * cc };
            Rw[wv][lane][0][0] = { ca * T00.re + sa * T10.im, ca * T00.im - sa * T10.re };
            Rw[wv][lane][0][1] = { ca * T01.re + sa * T11.im, ca * T01.im - sa * T11.re };
            Rw[wv][lane][1][0] = { sa * T00.im + ca * T10.re, -sa * T00.re + ca * T10.im };
            Rw[wv][lane][1][1] = { sa * T01.im + ca * T11.re, -sa * T01.re + ca * T11.im };
        }
    } else if (lane < 10) {
        const int h = lane - 8;                 // layer half 0/1
        const int l = q + h * 4;
        if (l < 6) {
            float s, c;
            sincosf(w_U[l], &s, &c);
            ISw[wv][h][0] = c;
            ISw[wv][h][1] = s;
        }
    }
    WSYNC();                                    // wave-local dep only

    // ---- Phase 2: L[l] build from OWN wave's gate slots ----
    for (int l = q; l < 6; l += 4) {
        const int sb = (l == q) ? 0 : 4;        // slot base for this layer
        const int code = (int)((0xD89C8DC98DC9ULL >> (8 * l)) & 0xFF);
        const int qa = code & 3, qb = (code >> 2) & 3;
        const int qr = (code >> 4) & 3, qs = (code >> 6) & 3;
        const int uAi = (((i >> (3 - qa)) & 1) << 1) | ((i >> (3 - qb)) & 1);
        const int uAj = (((j >> (3 - qa)) & 1) << 1) | ((j >> (3 - qb)) & 1);
        const int uBi = (((i >> (3 - qr)) & 1) << 1) | ((i >> (3 - qs)) & 1);
        const int uBj = (((j >> (3 - qr)) & 1) << 1) | ((j >> (3 - qs)) & 1);
        cpx ga;
        if (uAj == 0)      ga = cmul(Rw[wv][sb + qa][uAi >> 1][0], Rw[wv][sb + qb][uAi & 1][0]);
        else if (uAj == 3) ga = cmul(Rw[wv][sb + qa][uAi >> 1][1], Rw[wv][sb + qb][uAi & 1][1]);
        else {
            const cpx k1 = cmul(Rw[wv][sb + qa][uAi >> 1][0], Rw[wv][sb + qb][uAi & 1][1]);
            const cpx k2 = cmul(Rw[wv][sb + qa][uAi >> 1][1], Rw[wv][sb + qb][uAi & 1][0]);
            const cpx tc = (uAj == 1) ? k1 : k2;   // * cos
            const cpx ts = (uAj == 1) ? k2 : k1;   // * i sin
            const float c = ISw[wv][sb ? 1 : 0][0], s = ISw[wv][sb ? 1 : 0][1];
            ga.re = c * tc.re - s * ts.im;
            ga.im = c * tc.im + s * ts.re;
        }
        const cpx gb = cmul(Rw[wv][sb + qr][uBi >> 1][uBj >> 1],
                            Rw[wv][sb + qs][uBi & 1][uBj & 1]);
        L[l][i][j] = cmul(ga, gb);
    }
    BAR();

    // ---- Phase 3: Pp[q][m] = quarter-k partial of L[2m+1]*L[2m] ----
    {
        cpx a0 = {0.f, 0.f}, a1 = {0.f, 0.f}, a2 = {0.f, 0.f};
        #pragma unroll
        for (int kk = 0; kk < 4; ++kk) {
            const int k = k0 + kk;
            a0 = cfma_(a0, L[1][i][k], L[0][k][j]);
            a1 = cfma_(a1, L[3][i][k], L[2][k][j]);
            a2 = cfma_(a2, L[5][i][k], L[4][k][j]);
        }
        Pp[q][0][i][j] = a0; Pp[q][1][i][j] = a1; Pp[q][2][i][j] = a2;
    }
    BAR();

    // ---- Phase 3b: reduce 4 partials (768 items, ascending q order) ----
    if (tid < 768) {
        const int m = tid >> 8, e = tid & 255, i2 = e >> 4, j2 = e & 15;
        cpx s = Pp[0][m][i2][j2];
        #pragma unroll
        for (int u = 1; u < 4; ++u) {
            const cpx t = Pp[u][m][i2][j2];
            s.re += t.re; s.im += t.im;
        }
        P1[m][i2][j2] = s;
    }
    BAR();

    // ---- Phase 4: PART[q] = quarter-k partial of P1[1]*P1[0] ----
    {
        cpx acc = {0.f, 0.f};
        #pragma unroll
        for (int kk = 0; kk < 4; ++kk) {
            const int k = k0 + kk;
            acc = cfma_(acc, P1[1][i][k], P1[0][k][j]);
        }
        PART[q][i][j] = acc;
    }
    BAR();
    if (tid < 256) {
        cpx s = PART[0][i][j];
        #pragma unroll
        for (int u = 1; u < 4; ++u) {
            const cpx t = PART[u][i][j];
            s.re += t.re; s.im += t.im;
        }
        Dm[i][j] = s;
    }
    BAR();

    // ---- Phase 5: W = P1[2]*D (same split) ----
    {
        cpx acc = {0.f, 0.f};
        #pragma unroll
        for (int kk = 0; kk < 4; ++kk) {
            const int k = k0 + kk;
            acc = cfma_(acc, P1[2][i][k], Dm[k][j]);
        }
        PART[q][i][j] = acc;
    }
    BAR();
    if (tid < 256) {
        cpx s = PART[0][i][j];
        #pragma unroll
        for (int u = 1; u < 4; ++u) {
            const cpx t = PART[u][i][j];
            s.re += t.re; s.im += t.im;
        }
        Wf[i][j] = s;
    }
    BAR();

    // ---- Phase 6: M[i][j] = sum_k zk conj(W[k][i]) W[k][j] (same split) ----
    {
        cpx acc = {0.f, 0.f};
        #pragma unroll
        for (int kk = 0; kk < 4; ++kk) {
            const int k = k0 + kk;
            const float zk = (k < 8) ? 1.f : -1.f;
            const cpx a = Wf[k][i];
            const cpx b = Wf[k][j];
            acc.re += zk * (a.re * b.re + a.im * b.im);   // conj(a)*b
            acc.im += zk * (a.re * b.im - a.im * b.re);
        }
        PART[q][i][j] = acc;
    }
    BAR();
    if (tid < 256) {
        cpx s = PART[0][i][j];
        #pragma unroll
        for (int u = 1; u < 4; ++u) {
            const cpx t = PART[u][i][j];
            s.re += t.re; s.im += t.im;
        }
        Mm[i][j] = s;
    }
    BAR();

    // ---- Phase 7: Pauli-trace partials over col quarter (p = ct) ----
    {
        const int p = ct;
        float accre = 0.f;
        #pragma unroll
        for (int cc = 0; cc < 4; ++cc) {
            const int col = k0 + cc;
            int row = 0;
            cpx val = {1.f, 0.f};
            #pragma unroll
            for (int k = 0; k < 4; ++k) {
                const int pk = (p >> (6 - 2 * k)) & 3;
                const int b = (col >> (3 - k)) & 1;
                int rb = b;
                if (pk == 1) {
                    rb = b ^ 1;
                } else if (pk == 2) {
                    rb = b ^ 1;
                    const cpx fc = {0.f, b ? -1.f : 1.f};
                    val = cmul(val, fc);
                } else if (pk == 3) {
                    if (b) { val.re = -val.re; val.im = -val.im; }
                }
                row |= rb << (3 - k);
            }
            const cpx mv = Mm[col][row];
            accre += mv.re * val.re - mv.im * val.im;
        }
        cpp[p][q] = accre;
    }
    BAR();

    // ---- Phase 8: collapse with inline 4-partial sums (R14 order) ----
    if (tid < 125) {
        const int cnt = TAB.cnt[tid];
        float s = 0.f;
        for (int k = 0; k < cnt; ++k) {        // ascending: deterministic
            const float* v = cpp[TAB.idx[tid][k]];
            s += (v[0] + v[1] + v[2] + v[3]) * (1.f / 16.f);
        }
        cf[tid] = s;
    }
    BAR();

    // ---- eval: prep + 2 elements per thread from LDS coefficients ----
    if (idx >= B2) return;
    const float scale = scale_p[0], bias = bias_p[0];

    float2 res;
    #pragma unroll
    for (int e = 0; e < 2; ++e) {
        const float f0 = e ? f.z : f.x;    // vmcnt waited here, fully hidden
        const float f1 = e ? f.w : f.y;
        float s0, c0, s1, c1;
        sincosf(f0, &s0, &c0);
        sincosf(f1, &s1, &c1);
        const float x = s1 * c0, y = s1 * s0, z = c1;

        float xp[5], yp[5], zp[5];
        xp[0] = yp[0] = zp[0] = 1.f;
        #pragma unroll
        for (int k = 1; k < 5; ++k) {
            xp[k] = xp[k - 1] * x;
            yp[k] = yp[k - 1] * y;
            zp[k] = zp[k - 1] * z;
        }

        float Z = 0.f;
        #pragma unroll
        for (int a = 0; a <= 4; ++a)
            #pragma unroll
            for (int b = 0; b <= 4 - a; ++b)
                #pragma unroll
                for (int c = 0; c <= 4 - a - b; ++c)
                    Z = fmaf(cf[(a * 5 + b) * 5 + c], xp[a] * yp[b] * zp[c], Z);

        const float noise = 0.04472135954999579f * (Z * Z - 1.f) * 0.25f;
        const float v = scale * (Z + noise) + bias;
        if (e) res.y = v; else res.x = v;
    }
    out2[idx] = res;
}

extern "C" void kernel_launch(void* const* d_in, const int* in_sizes, int n_in,
                              void* d_out, int out_size, void* d_ws, size_t ws_size,
                              hipStream_t stream) {
    const float* inputs  = (const float*)d_in[0];   // [B,2] f32
    const float* w_U     = (const float*)d_in[1];   // [6]
    const float* w_RXZX  = (const float*)d_in[2];   // [6,4,3]
    const float* scale_p = (const float*)d_in[3];   // [1]
    const float* bias_p  = (const float*)d_in[4];   // [1]
    float* out = (float*)d_out;

    const int B  = in_sizes[0] / 2;                 // elements
    const int B2 = B / 2;                           // float4 units (2 el/thr)
    const int nblocks = (B2 + 1023) / 1024;         // 256 (= CU count)

    fused_kernel<<<nblocks, 1024, 0, stream>>>(
        (const float4*)inputs, w_U, w_RXZX, scale_p, bias_p, (float2*)out, B2);
}

// Round 22
// 16.448 us; speedup vs baseline: 1.1899x; 1.0520x over previous
//
#include <hip/hip_runtime.h>
#include <math.h>

// ---------------------------------------------------------------------------
// Z_exp = Tr(M rho^x4) = degree-4 poly in Bloch (x,y,z), 35 monomials.
// FINAL (= R14, best measured 16.56us): fused single dispatch, 256 blocks x
// 1024 threads, chain k-SPLIT 4 ways (per-lane work /4, 4 waves/SIMD TLP),
// 13 barrier phases, eval prep before chain, 2 elements/thread.
// Plateau evidence (R14-R21): all phase/ILP/occupancy/grid levers measured
// neutral or worse; cost = launch + latency-bound phase chain + tail, not a
// HW roofline (HBM 0.1%, VALU 8%).
// ---------------------------------------------------------------------------

struct cpx { float re, im; };

__device__ __forceinline__ cpx cmul(cpx a, cpx b) {
    return { a.re * b.re - a.im * b.im, a.re * b.im + a.im * b.re };
}
__device__ __forceinline__ cpx cfma_(cpx acc, cpx a, cpx b) {
    acc.re += a.re * b.re - a.im * b.im;
    acc.im += a.re * b.im + a.im * b.re;
    return acc;
}

// ---- compile-time Pauli-string -> monomial grouping (data-independent) ----
struct MonoTab { unsigned char cnt[125]; unsigned char idx[125][24]; };

constexpr int mono_of(int p) {
    int a = 0, b = 0, c = 0;
    for (int k = 0; k < 4; ++k) {
        const int pk = (p >> (2 * k)) & 3;   // 0=I,1=X,2=Y,3=Z
        a += (pk == 1); b += (pk == 2); c += (pk == 3);
    }
    return (a * 5 + b) * 5 + c;
}
constexpr MonoTab build_tab() {
    MonoTab t{};
    for (int m = 0; m < 125; ++m) {
        t.cnt[m] = 0;
        for (int k = 0; k < 24; ++k) t.idx[m][k] = 0;
    }
    for (int p = 0; p < 256; ++p) {          // ascending p: fixed sum order
        const int m = mono_of(p);
        t.idx[m][t.cnt[m]++] = (unsigned char)p;
    }
    return t;
}
__constant__ const MonoTab TAB = build_tab();

__global__ __launch_bounds__(1024) void fused_kernel(
    const float4* __restrict__ in4, const float* __restrict__ w_U,
    const float* __restrict__ w_RXZX, const float* __restrict__ scale_p,
    const float* __restrict__ bias_p, float2* __restrict__ out2, int B2)
{
    __shared__ cpx   R[24][2][2];
    __shared__ float ISc[6], ISs[6];
    __shared__ cpx   L[6][16][16];
    __shared__ cpx   Pp[4][3][16][16];   // phase-3 partials (reused as PART)
    __shared__ cpx   P1[3][16][16];
    __shared__ cpx   Dm[16][16];
    __shared__ cpx   Wf[16][16];
    __shared__ cpx   Mm[16][16];
    __shared__ float cpp[4][256];        // phase-7 partials
    __shared__ float cp[256];
    __shared__ float cf[125];

    cpx (*PART)[16][16] = (cpx(*)[16][16])Pp;   // reuse Pp after phase 3b

    const int tid = threadIdx.x;
    const int idx = blockIdx.x * 1024 + tid;    // float4 unit (2 elements)
    const int q  = tid >> 8;                    // k-quarter 0..3
    const int ct = tid & 255;
    const int i = ct >> 4, j = ct & 15;
    const int k0 = q << 2;

    // ---- eval prep (all threads, before the chain) ----
    float4 f = make_float4(0.f, 0.f, 0.f, 0.f);
    if (idx < B2) f = in4[idx];
    const float scale = scale_p[0], bias = bias_p[0];
    float xp[2][5], yp[2][5], zp[2][5];
    #pragma unroll
    for (int e = 0; e < 2; ++e) {
        const float f0 = e ? f.z : f.x;
        const float f1 = e ? f.w : f.y;
        float s0, c0, s1, c1;
        sincosf(f0, &s0, &c0);
        sincosf(f1, &s1, &c1);
        const float x = s1 * c0, y = s1 * s0, z = c1;
        xp[e][0] = yp[e][0] = zp[e][0] = 1.f;
        #pragma unroll
        for (int k = 1; k < 5; ++k) {
            xp[e][k] = xp[e][k - 1] * x;
            yp[e][k] = yp[e][k - 1] * y;
            zp[e][k] = zp[e][k - 1] * z;
        }
    }

    // ---- Phase 1: 2x2 RXZX gates + iSWAP params ----
    if (tid < 24) {
        const float ta = w_RXZX[tid * 3 + 0];
        const float tb = w_RXZX[tid * 3 + 1];
        const float tc = w_RXZX[tid * 3 + 2];
        float sa, ca, sb, cb, sc, cc;
        sincosf(0.5f * ta, &sa, &ca);
        sincosf(0.5f * tb, &sb, &cb);
        sincosf(0.5f * tc, &sc, &cc);
        // RX(t)=[[c,-is],[-is,c]], RZ(t)=diag(c-is,c+is); g = RX(a)RZ(b)RX(c)
        const cpx e0 = { cb, -sb };
        const cpx e1 = { cb,  sb };
        const cpx T00 = { e0.re * cc, e0.im * cc };
        const cpx T01 = { -e0.im * (-sc), e0.re * (-sc) };
        const cpx T10 = { -e1.im * (-sc), e1.re * (-sc) };
        const cpx T11 = { e1.re * cc, e1.im * cc };
        R[tid][0][0] = { ca * T00.re + sa * T10.im, ca * T00.im - sa * T10.re };
        R[tid][0][1] = { ca * T01.re + sa * T11.im, ca * T01.im - sa * T11.re };
        R[tid][1][0] = { sa * T00.im + ca * T10.re, -sa * T00.re + ca * T10.im };
        R[tid][1][1] = { sa * T01.im + ca * T11.re, -sa * T01.re + ca * T11.im };
    } else if (tid < 30) {
        const int l = tid - 24;
        float s, c;
        sincosf(w_U[l], &s, &c);
        ISc[l] = c;
        ISs[l] = s;
    }
    __syncthreads();

    // ---- Phase 2: L[l] build; group q handles l = q, q+4 ----
    for (int l = q; l < 6; l += 4) {
        const int code = (int)((0xD89C8DC98DC9ULL >> (8 * l)) & 0xFF);
        const int qa = code & 3, qb = (code >> 2) & 3;
        const int qr = (code >> 4) & 3, qs = (code >> 6) & 3;
        const int uAi = (((i >> (3 - qa)) & 1) << 1) | ((i >> (3 - qb)) & 1);
        const int uAj = (((j >> (3 - qa)) & 1) << 1) | ((j >> (3 - qb)) & 1);
        const int uBi = (((i >> (3 - qr)) & 1) << 1) | ((i >> (3 - qs)) & 1);
        const int uBj = (((j >> (3 - qr)) & 1) << 1) | ((j >> (3 - qs)) & 1);
        const int ra = l * 4 + qa, rb = l * 4 + qb;
        cpx ga;
        if (uAj == 0)      ga = cmul(R[ra][uAi >> 1][0], R[rb][uAi & 1][0]);
        else if (uAj == 3) ga = cmul(R[ra][uAi >> 1][1], R[rb][uAi & 1][1]);
        else {
            const cpx k1 = cmul(R[ra][uAi >> 1][0], R[rb][uAi & 1][1]);
            const cpx k2 = cmul(R[ra][uAi >> 1][1], R[rb][uAi & 1][0]);
            const cpx tc = (uAj == 1) ? k1 : k2;   // * cos
            const cpx ts = (uAj == 1) ? k2 : k1;   // * i sin
            const float c = ISc[l], s = ISs[l];
            ga.re = c * tc.re - s * ts.im;
            ga.im = c * tc.im + s * ts.re;
        }
        const cpx gb = cmul(R[l * 4 + qr][uBi >> 1][uBj >> 1],
                            R[l * 4 + qs][uBi & 1][uBj & 1]);
        L[l][i][j] = cmul(ga, gb);
    }
    __syncthreads();

    // ---- Phase 3: Pp[q][m] = quarter-k partial of L[2m+1]*L[2m] ----
    {
        cpx a0 = {0.f, 0.f}, a1 = {0.f, 0.f}, a2 = {0.f, 0.f};
        #pragma unroll
        for (int kk = 0; kk < 4; ++kk) {
            const int k = k0 + kk;
            a0 = cfma_(a0, L[1][i][k], L[0][k][j]);
            a1 = cfma_(a1, L[3][i][k], L[2][k][j]);
            a2 = cfma_(a2, L[5][i][k], L[4][k][j]);
        }
        Pp[q][0][i][j] = a0; Pp[q][1][i][j] = a1; Pp[q][2][i][j] = a2;
    }
    __syncthreads();

    // ---- Phase 3b: reduce 4 partials (768 items, ascending q order) ----
    if (tid < 768) {
        const int m = tid >> 8, e = tid & 255, i2 = e >> 4, j2 = e & 15;
        cpx s = Pp[0][m][i2][j2];
        #pragma unroll
        for (int u = 1; u < 4; ++u) {
            const cpx t = Pp[u][m][i2][j2];
            s.re += t.re; s.im += t.im;
        }
        P1[m][i2][j2] = s;
    }
    __syncthreads();

    // ---- Phase 4: PART[q] = quarter-k partial of P1[1]*P1[0] ----
    {
        cpx acc = {0.f, 0.f};
        #pragma unroll
        for (int kk = 0; kk < 4; ++kk) {
            const int k = k0 + kk;
            acc = cfma_(acc, P1[1][i][k], P1[0][k][j]);
        }
        PART[q][i][j] = acc;
    }
    __syncthreads();
    if (tid < 256) {
        cpx s = PART[0][i][j];
        #pragma unroll
        for (int u = 1; u < 4; ++u) {
            const cpx t = PART[u][i][j];
            s.re += t.re; s.im += t.im;
        }
        Dm[i][j] = s;
    }
    __syncthreads();

    // ---- Phase 5: W = P1[2]*D (same split) ----
    {
        cpx acc = {0.f, 0.f};
        #pragma unroll
        for (int kk = 0; kk < 4; ++kk) {
            const int k = k0 + kk;
            acc = cfma_(acc, P1[2][i][k], Dm[k][j]);
        }
        PART[q][i][j] = acc;
    }
    __syncthreads();
    if (tid < 256) {
        cpx s = PART[0][i][j];
        #pragma unroll
        for (int u = 1; u < 4; ++u) {
            const cpx t = PART[u][i][j];
            s.re += t.re; s.im += t.im;
        }
        Wf[i][j] = s;
    }
    __syncthreads();

    // ---- Phase 6: M[i][j] = sum_k zk conj(W[k][i]) W[k][j] (same split) ----
    {
        cpx acc = {0.f, 0.f};
        #pragma unroll
        for (int kk = 0; kk < 4; ++kk) {
            const int k = k0 + kk;
            const float zk = (k < 8) ? 1.f : -1.f;
            const cpx a = Wf[k][i];
            const cpx b = Wf[k][j];
            acc.re += zk * (a.re * b.re + a.im * b.im);   // conj(a)*b
            acc.im += zk * (a.re * b.im - a.im * b.re);
        }
        PART[q][i][j] = acc;
    }
    __syncthreads();
    if (tid < 256) {
        cpx s = PART[0][i][j];
        #pragma unroll
        for (int u = 1; u < 4; ++u) {
            const cpx t = PART[u][i][j];
            s.re += t.re; s.im += t.im;
        }
        Mm[i][j] = s;
    }
    __syncthreads();

    // ---- Phase 7: Pauli-trace partials over col quarter (p = ct) ----
    {
        const int p = ct;
        float accre = 0.f;
        #pragma unroll
        for (int cc = 0; cc < 4; ++cc) {
            const int col = k0 + cc;
            int row = 0;
            cpx val = {1.f, 0.f};
            #pragma unroll
            for (int k = 0; k < 4; ++k) {
                const int pk = (p >> (6 - 2 * k)) & 3;
                const int b = (col >> (3 - k)) & 1;
                int rb = b;
                if (pk == 1) {
                    rb = b ^ 1;
                } else if (pk == 2) {
                    rb = b ^ 1;
                    const cpx fc = {0.f, b ? -1.f : 1.f};
                    val = cmul(val, fc);
                } else if (pk == 3) {
                    if (b) { val.re = -val.re; val.im = -val.im; }
                }
                row |= rb << (3 - k);
            }
            const cpx mv = Mm[col][row];
            accre += mv.re * val.re - mv.im * val.im;
        }
        cpp[q][p] = accre;
    }
    __syncthreads();
    if (tid < 256) {
        float s = cpp[0][tid];
        #pragma unroll
        for (int u = 1; u < 4; ++u) s += cpp[u][tid];
        cp[tid] = s * (1.f / 16.f);
    }
    __syncthreads();

    // ---- Phase 8: collapse via compile-time table ----
    if (tid < 125) {
        const int cnt = TAB.cnt[tid];
        float s = 0.f;
        for (int k = 0; k < cnt; ++k)          // ascending: deterministic
            s += cp[TAB.idx[tid][k]];
        cf[tid] = s;
    }
    __syncthreads();

    // ---- eval finish: 2 elements per thread from LDS coefficients ----
    if (idx >= B2) return;

    float2 res;
    #pragma unroll
    for (int e = 0; e < 2; ++e) {
        float Z = 0.f;
        #pragma unroll
        for (int a = 0; a <= 4; ++a)
            #pragma unroll
            for (int b = 0; b <= 4 - a; ++b)
                #pragma unroll
                for (int c = 0; c <= 4 - a - b; ++c)
                    Z = fmaf(cf[(a * 5 + b) * 5 + c],
                             xp[e][a] * yp[e][b] * zp[e][c], Z);
        const float noise = 0.04472135954999579f * (Z * Z - 1.f) * 0.25f;
        const float v = scale * (Z + noise) + bias;
        if (e) res.y = v; else res.x = v;
    }
    out2[idx] = res;
}

extern "C" void kernel_launch(void* const* d_in, const int* in_sizes, int n_in,
                              void* d_out, int out_size, void* d_ws, size_t ws_size,
                              hipStream_t stream) {
    const float* inputs  = (const float*)d_in[0];   // [B,2] f32
    const float* w_U     = (const float*)d_in[1];   // [6]
    const float* w_RXZX  = (const float*)d_in[2];   // [6,4,3]
    const float* scale_p = (const float*)d_in[3];   // [1]
    const float* bias_p  = (const float*)d_in[4];   // [1]
    float* out = (float*)d_out;

    const int B  = in_sizes[0] / 2;                 // elements
    const int B2 = B / 2;                           // float4 units (2 el/thr)
    const int nblocks = (B2 + 1023) / 1024;         // 256 (= CU count)

    fused_kernel<<<nblocks, 1024, 0, stream>>>(
        (const float4*)inputs, w_U, w_RXZX, scale_p, bias_p, (float2*)out, B2);
}